// Round 1
// baseline (203.987 us; speedup 1.0000x reference)
//
#include <hip/hip_runtime.h>
#include <math.h>

#define BB 4
#define NN 2048
#define FF 128
#define HH 4
#define DD 32
#define NEG_SLOPE 0.2f

#define TN 32   // n-rows per attention block
#define TM 64   // m-tile

// K0: Wt[i][o] = W[o][i]
__global__ __launch_bounds__(128) void k_transpose_w(const float* __restrict__ W,
                                                     float* __restrict__ Wt) {
    int i = threadIdx.x;   // 0..127
    int o = blockIdx.x;    // 0..127
    Wt[i * FF + o] = W[o * FF + i];
}

// K1: h[row][o] = sum_i x[row][i] * Wt[i][o]; 32 rows per block, 256 threads,
// 4x4 register tile per thread. LDS: xs 16KB + wl 64KB = 80KB (1 block/CU).
__global__ __launch_bounds__(256) void k_gemm_h(const float* __restrict__ x,
                                                const float* __restrict__ Wt,
                                                float* __restrict__ h) {
    __shared__ float xs[32][FF];
    __shared__ float wl[FF][FF];   // [i][o]
    int t = threadIdx.x;
    long row0 = (long)blockIdx.x * 32;
#pragma unroll
    for (int k = 0; k < 4; ++k) {           // stage x: 1024 float4
        int q = t + k * 256;
        int r = q >> 5, c4 = q & 31;
        float4 v = ((const float4*)(x + (row0 + r) * FF))[c4];
        *(float4*)&xs[r][c4 * 4] = v;
    }
#pragma unroll
    for (int k = 0; k < 16; ++k) {          // stage Wt: 4096 float4
        int q = t + k * 256;
        int i = q >> 5, o4 = q & 31;
        float4 v = ((const float4*)(Wt + (long)i * FF))[o4];
        *(float4*)&wl[i][o4 * 4] = v;
    }
    __syncthreads();
    int og = t & 31;   // o = og*4 .. og*4+3
    int rg = t >> 5;   // rows rg*4 .. rg*4+3
    float acc[4][4];
#pragma unroll
    for (int a = 0; a < 4; ++a)
#pragma unroll
        for (int c = 0; c < 4; ++c) acc[a][c] = 0.f;
    for (int i = 0; i < FF; ++i) {
        float4 w4 = *(const float4*)&wl[i][og * 4];
#pragma unroll
        for (int a = 0; a < 4; ++a) {
            float xv = xs[rg * 4 + a][i];
            acc[a][0] += xv * w4.x;
            acc[a][1] += xv * w4.y;
            acc[a][2] += xv * w4.z;
            acc[a][3] += xv * w4.w;
        }
    }
#pragma unroll
    for (int a = 0; a < 4; ++a) {
        float4 o4 = {acc[a][0], acc[a][1], acc[a][2], acc[a][3]};
        *(float4*)(h + (row0 + rg * 4 + a) * FF + og * 4) = o4;
    }
}

// K2: e_src_t[b][hh][n], e_dst_t[b][hh][n] (transposed for coalesced staging in K3)
__global__ __launch_bounds__(256) void k_edges(const float* __restrict__ h,
                                               const float* __restrict__ a_src,
                                               const float* __restrict__ a_dst,
                                               float* __restrict__ es_t,
                                               float* __restrict__ ed_t) {
    __shared__ float as_[HH * DD], ad_[HH * DD];
    int t = threadIdx.x;
    if (t < HH * DD) { as_[t] = a_src[t]; ad_[t] = a_dst[t]; }
    __syncthreads();
    int g = blockIdx.x * 256 + t;        // 0 .. B*N*H-1
    int hh = g & (HH - 1);
    int n  = (g >> 2) & (NN - 1);
    int b  = g >> 13;                    // / (N*H)
    const float* hp = h + ((long)(b * NN + n)) * FF + hh * DD;
    float es = 0.f, ed = 0.f;
#pragma unroll
    for (int d4 = 0; d4 < DD / 4; ++d4) {
        float4 v = ((const float4*)hp)[d4];
        float4 s = *(const float4*)&as_[hh * DD + d4 * 4];
        float4 d = *(const float4*)&ad_[hh * DD + d4 * 4];
        es += v.x * s.x + v.y * s.y + v.z * s.z + v.w * s.w;
        ed += v.x * d.x + v.y * d.y + v.z * d.z + v.w * d.w;
    }
    es_t[(b * HH + hh) * NN + n] = es;
    ed_t[(b * HH + hh) * NN + n] = ed;
}

// K3: attention. grid (N/TN, H, B), 128 threads (2 waves).
// Per m-tile: phase1 stages h-tile + computes w = adj ? exp(leaky(es+ed)) : 0
// (one exp per (n,m)); phase2 does 2n x 4d register-tile PV accumulation.
// No max-subtraction needed: scores bounded ~|16| -> exp fits fp32 easily.
__global__ __launch_bounds__(128) void k_attn(const float* __restrict__ h,
                                              const int* __restrict__ adj,
                                              const float* __restrict__ es_t,
                                              const float* __restrict__ ed_t,
                                              float* __restrict__ out) {
    __shared__ float eds[NN];        // 8KB: all e_dst for this (b,head)
    __shared__ float ess[TN];
    __shared__ float wls[TM][TN];    // 8KB
    __shared__ float hls[TM][DD];    // 8KB
    int t = threadIdx.x;
    int n0 = blockIdx.x * TN;
    int head = blockIdx.y;
    int b = blockIdx.z;

    const float* edp = ed_t + (b * HH + head) * NN;
#pragma unroll
    for (int q = t; q < NN / 4; q += 128)
        ((float4*)eds)[q] = ((const float4*)edp)[q];
    if (t < TN) ess[t] = es_t[(b * HH + head) * NN + n0 + t];
    __syncthreads();

    float num[2][4];
    float den[2] = {0.f, 0.f};
#pragma unroll
    for (int j = 0; j < 2; ++j)
#pragma unroll
        for (int k = 0; k < 4; ++k) num[j][k] = 0.f;

    int tn = t >> 3;           // 0..15 -> rows n0 + tn*2 + {0,1}
    int td = t & 7;            // 0..7  -> d = td*4 .. +3
    const float* hbase = h + (long)b * NN * FF + head * DD;
    int n_w = t >> 2;          // 0..31: w-gen row
    int mmq = (t & 3) * 16;    // w-gen m-subrange
    float es_w = ess[n_w];

    for (int m0 = 0; m0 < NN; m0 += TM) {
        // phase 1a: stage h tile (TM x DD = 512 float4)
#pragma unroll
        for (int k = 0; k < 4; ++k) {
            int q = t + k * 128;
            int mm = q >> 3, c4 = q & 7;
            float4 v = *(const float4*)(hbase + (long)(m0 + mm) * FF + c4 * 4);
            *(float4*)&hls[mm][c4 * 4] = v;
        }
        // phase 1b: w generation (16 per thread, adj reads coalesced int4)
        {
            const int4* arow = (const int4*)(adj + (long)(n0 + n_w) * NN + m0 + mmq);
#pragma unroll
            for (int jq = 0; jq < 4; ++jq) {
                int4 a4 = arow[jq];
#pragma unroll
                for (int jj = 0; jj < 4; ++jj) {
                    int mm = mmq + jq * 4 + jj;
                    int a = (&a4.x)[jj];
                    float s = es_w + eds[m0 + mm];
                    s = s > 0.f ? s : NEG_SLOPE * s;
                    float w = a ? __expf(s) : 0.f;
                    wls[mm][n_w] = w;
                }
            }
        }
        __syncthreads();
        // phase 2: PV accumulate
#pragma unroll 8
        for (int mm = 0; mm < TM; ++mm) {
            float2 w2 = *(const float2*)&wls[mm][tn * 2];
            float4 h4 = *(const float4*)&hls[mm][td * 4];
            num[0][0] += w2.x * h4.x;
            num[0][1] += w2.x * h4.y;
            num[0][2] += w2.x * h4.z;
            num[0][3] += w2.x * h4.w;
            num[1][0] += w2.y * h4.x;
            num[1][1] += w2.y * h4.y;
            num[1][2] += w2.y * h4.z;
            num[1][3] += w2.y * h4.w;
            den[0] += w2.x;
            den[1] += w2.y;
        }
        __syncthreads();
    }
#pragma unroll
    for (int j = 0; j < 2; ++j) {
        int n = n0 + tn * 2 + j;
        float inv = 1.0f / den[j];
        float4 o4 = {num[j][0] * inv, num[j][1] * inv,
                     num[j][2] * inv, num[j][3] * inv};
        *(float4*)(out + ((long)(b * NN + n)) * FF + head * DD + td * 4) = o4;
    }
}

extern "C" void kernel_launch(void* const* d_in, const int* in_sizes, int n_in,
                              void* d_out, int out_size, void* d_ws, size_t ws_size,
                              hipStream_t stream) {
    const float* x     = (const float*)d_in[0];
    const int*   adj   = (const int*)d_in[1];
    const float* W     = (const float*)d_in[2];
    const float* a_src = (const float*)d_in[3];
    const float* a_dst = (const float*)d_in[4];
    float* out = (float*)d_out;

    float* h    = (float*)d_ws;                       // B*N*F   = 1,048,576 floats
    float* Wt   = h + (size_t)BB * NN * FF;           // F*F     = 16,384
    float* es_t = Wt + (size_t)FF * FF;               // B*H*N   = 32,768
    float* ed_t = es_t + (size_t)BB * HH * NN;        // B*H*N   = 32,768

    hipLaunchKernelGGL(k_transpose_w, dim3(FF), dim3(FF), 0, stream, W, Wt);
    hipLaunchKernelGGL(k_gemm_h, dim3(BB * NN / 32), dim3(256), 0, stream, x, Wt, h);
    hipLaunchKernelGGL(k_edges, dim3(BB * NN * HH / 256), dim3(256), 0, stream,
                       h, a_src, a_dst, es_t, ed_t);
    hipLaunchKernelGGL(k_attn, dim3(NN / TN, HH, BB), dim3(128), 0, stream,
                       h, adj, es_t, ed_t, out);
}

// Round 2
// 111.639 us; speedup vs baseline: 1.8272x; 1.8272x over previous
//
#include <hip/hip_runtime.h>
#include <math.h>

#define BB 4
#define NN 2048
#define FF 128
#define HH 4
#define DD 32
#define NEG_SLOPE 0.2f
#define LOG2E 1.4426950408889634f

typedef __attribute__((ext_vector_type(8))) short short8;
typedef __attribute__((ext_vector_type(4))) float floatx4;

__device__ __forceinline__ float exp2_fast(float x) {
#if __has_builtin(__builtin_amdgcn_exp2f)
    return __builtin_amdgcn_exp2f(x);
#else
    return exp2f(x);
#endif
}

// ---------------- K1: h = x @ W^T  (fp32, W transposed on the fly into LDS)
// 16 rows/block, 256 threads, grid 512. LDS: xs 8KB + wt 17KB.
__global__ __launch_bounds__(256) void k_gemm_h(const float* __restrict__ x,
                                                const float* __restrict__ W,
                                                float* __restrict__ h) {
    __shared__ float xs[16][FF];
    __shared__ float wt[32][132];   // [i_local][o], pad 4
    int t = threadIdx.x;
    long rows0 = (long)blockIdx.x * 16;
#pragma unroll
    for (int k = 0; k < 2; ++k) {               // 512 float4 of x
        int q = t + k * 256;
        int r = q >> 5, c4 = q & 31;
        float4 v = ((const float4*)(x + (rows0 + r) * FF))[c4];
        *(float4*)&xs[r][c4 * 4] = v;
    }
    int og = t & 31, rg = t >> 5;               // cols og*4.., rows rg*2..
    float acc[2][4];
#pragma unroll
    for (int a = 0; a < 2; ++a)
#pragma unroll
        for (int c = 0; c < 4; ++c) acc[a][c] = 0.f;

    int wo = t & 127, wg = t >> 7;              // staging roles
    for (int i0 = 0; i0 < FF; i0 += 32) {
        __syncthreads();
        // stage W[o][i0..i0+31] transposed -> wt[i][o]
#pragma unroll
        for (int u = 0; u < 4; ++u) {
            float4 v = *(const float4*)(W + (long)wo * FF + i0 + wg * 16 + u * 4);
            wt[wg * 16 + u * 4 + 0][wo] = v.x;
            wt[wg * 16 + u * 4 + 1][wo] = v.y;
            wt[wg * 16 + u * 4 + 2][wo] = v.z;
            wt[wg * 16 + u * 4 + 3][wo] = v.w;
        }
        __syncthreads();
#pragma unroll
        for (int i = 0; i < 32; ++i) {
            float4 w4 = *(const float4*)&wt[i][og * 4];
            float x0 = xs[rg * 2 + 0][i0 + i];
            float x1 = xs[rg * 2 + 1][i0 + i];
            acc[0][0] += x0 * w4.x; acc[0][1] += x0 * w4.y;
            acc[0][2] += x0 * w4.z; acc[0][3] += x0 * w4.w;
            acc[1][0] += x1 * w4.x; acc[1][1] += x1 * w4.y;
            acc[1][2] += x1 * w4.z; acc[1][3] += x1 * w4.w;
        }
    }
#pragma unroll
    for (int a = 0; a < 2; ++a) {
        float4 o4 = {acc[a][0], acc[a][1], acc[a][2], acc[a][3]};
        *(float4*)(h + (rows0 + rg * 2 + a) * FF + og * 4) = o4;
    }
}

// ---------------- K2: edge scores, prescaled by log2(e), transposed layout
__global__ __launch_bounds__(256) void k_edges(const float* __restrict__ h,
                                               const float* __restrict__ a_src,
                                               const float* __restrict__ a_dst,
                                               float* __restrict__ es_t,
                                               float* __restrict__ ed_t) {
    __shared__ float as_[HH * DD], ad_[HH * DD];
    int t = threadIdx.x;
    if (t < HH * DD) { as_[t] = a_src[t]; ad_[t] = a_dst[t]; }
    __syncthreads();
    int g = blockIdx.x * 256 + t;
    int hh = g & (HH - 1);
    int n  = (g >> 2) & (NN - 1);
    int b  = g >> 13;
    const float* hp = h + ((long)(b * NN + n)) * FF + hh * DD;
    float es = 0.f, ed = 0.f;
#pragma unroll
    for (int d4 = 0; d4 < DD / 4; ++d4) {
        float4 v = ((const float4*)hp)[d4];
        float4 s = *(const float4*)&as_[hh * DD + d4 * 4];
        float4 d = *(const float4*)&ad_[hh * DD + d4 * 4];
        es += v.x * s.x + v.y * s.y + v.z * s.z + v.w * s.w;
        ed += v.x * d.x + v.y * d.y + v.z * d.z + v.w * d.w;
    }
    es_t[(b * HH + hh) * NN + n] = es * LOG2E;
    ed_t[(b * HH + hh) * NN + n] = ed * LOG2E;
}

// ---------------- K3: pack adj into bitmask words bits[n][NN/32]
__global__ __launch_bounds__(256) void k_pack_adj(const int* __restrict__ adj,
                                                  unsigned int* __restrict__ bits) {
    int idx = blockIdx.x * 256 + threadIdx.x;   // 0 .. N*64-1
    int n = idx >> 6, w = idx & 63;
    const int4* base = (const int4*)(adj + (size_t)n * NN + w * 32);
    unsigned int word = 0;
#pragma unroll
    for (int q = 0; q < 8; ++q) {
        int4 a = base[q];
        word |= ((unsigned int)(a.x & 1)) << (q * 4 + 0);
        word |= ((unsigned int)(a.y & 1)) << (q * 4 + 1);
        word |= ((unsigned int)(a.z & 1)) << (q * 4 + 2);
        word |= ((unsigned int)(a.w & 1)) << (q * 4 + 3);
    }
    bits[idx] = word;
}

// wait: bit j must correspond to column w*32+j. Rewrite below properly.

// ---------------- K4: ht[bh][d][m] = bf16(h[b][m][head*32+d]) (RTNE), transposed
__global__ __launch_bounds__(256) void k_ht(const float* __restrict__ h,
                                            unsigned short* __restrict__ ht) {
    __shared__ unsigned short tile[DD][136];   // [d][m_local], pad 8
    int t = threadIdx.x;
    int m0 = blockIdx.x * 128;
    int bh = blockIdx.y;
    int b = bh >> 2, head = bh & 3;
    int m_l = t >> 1, g = (t & 1) * 16;
    const float* hp = h + ((long)(b * NN + m0 + m_l)) * FF + head * DD + g;
#pragma unroll
    for (int u = 0; u < 4; ++u) {
        float4 v = *(const float4*)(hp + u * 4);
#pragma unroll
        for (int e = 0; e < 4; ++e) {
            float f = (&v.x)[e];
            unsigned int ui = __float_as_uint(f);
            ui += 0x7FFFu + ((ui >> 16) & 1u);   // RTNE to bf16
            tile[g + u * 4 + e][m_l] = (unsigned short)(ui >> 16);
        }
    }
    __syncthreads();
    int d = t >> 3, c = t & 7;
    unsigned short* op = ht + ((size_t)bh * DD + d) * NN + m0;
#pragma unroll
    for (int k = 0; k < 2; ++k) {
        int4 v = *(const int4*)&tile[d][(c + k * 8) * 8];
        *(int4*)(op + (c + k * 8) * 8) = v;
    }
}

// ---------------- K5: fused masked-softmax attention + PV via MFMA
// grid (16 n-blocks, 16 bh), 512 threads (8 waves), 1 block/CU.
// Wave w owns n-rows n0 + w*16 .. +15. Full ht for this bh staged in LDS
// (stride-padded), e_dst staged in LDS; zero barriers in the m-loop.
#define HSTRIDE 2056
__global__ __launch_bounds__(512, 2) void k_attn(
        const unsigned short* __restrict__ ht,
        const unsigned int* __restrict__ bits,
        const float* __restrict__ es_t,
        const float* __restrict__ ed_t,
        float* __restrict__ out) {
    __shared__ unsigned short hb[DD * HSTRIDE];   // 128.5 KB
    __shared__ float eds[NN];                      // 8 KB
    int t = threadIdx.x;
    int n0 = blockIdx.x * 128;
    int bh = blockIdx.y;
    int b = bh >> 2, head = bh & 3;

    // stage e_dst' (prescaled)
    {
        float4 v = ((const float4*)(ed_t + (size_t)bh * NN))[t];
        *(float4*)&eds[t * 4] = v;
    }
    // stage ht -> hb (row-padded)
    {
        const unsigned short* htp = ht + (size_t)bh * DD * NN;
        int d = t >> 4, c = t & 15;
#pragma unroll
        for (int k = 0; k < 16; ++k) {
            int ch = c + k * 16;          // 0..255 chunks of 8 bf16
            int4 v = *(const int4*)(htp + (size_t)d * NN + ch * 8);
            *(int4*)&hb[d * HSTRIDE + ch * 8] = v;
        }
    }
    __syncthreads();

    int wid = t >> 6, lane = t & 63;
    int q = lane >> 4, r = lane & 15;
    int n = n0 + wid * 16 + r;
    float es = es_t[(size_t)bh * NN + n];
    const unsigned int* brow = bits + (size_t)n * (NN / 32);

    floatx4 acc0 = {0.f, 0.f, 0.f, 0.f};
    floatx4 acc1 = {0.f, 0.f, 0.f, 0.f};
    floatx4 accd = {0.f, 0.f, 0.f, 0.f};
    union { short8 s8; int i[4]; } ones;
    ones.i[0] = 0x3F803F80; ones.i[1] = 0x3F803F80;
    ones.i[2] = 0x3F803F80; ones.i[3] = 0x3F803F80;

    int qo = q * 8;
#pragma unroll 2
    for (int m0 = 0; m0 < NN; m0 += 32) {
        unsigned int word = brow[m0 >> 5];
        float4 e0 = *(const float4*)&eds[m0 + qo];
        float4 e1 = *(const float4*)&eds[m0 + qo + 4];
        float w[8];
#pragma unroll
        for (int j = 0; j < 8; ++j) {
            float ev = j < 4 ? (&e0.x)[j] : (&e1.x)[j - 4];
            float s = es + ev;
            float l = fmaxf(s, NEG_SLOPE * s);
            float v = exp2_fast(l);
            unsigned int bit = (word >> (qo + j)) & 1u;
            unsigned int msk = 0u - bit;
            w[j] = __uint_as_float(__float_as_uint(v) & msk);
        }
        union { short8 s8; int i[4]; } af;
#pragma unroll
        for (int p = 0; p < 4; ++p)
            af.i[p] = __builtin_amdgcn_perm(__float_as_uint(w[2 * p + 1]),
                                            __float_as_uint(w[2 * p]),
                                            0x07060302u);  // [hi16(w0)|hi16(w1)]
        short8 b0 = *(const short8*)&hb[r * HSTRIDE + m0 + qo];
        short8 b1 = *(const short8*)&hb[(16 + r) * HSTRIDE + m0 + qo];
        acc0 = __builtin_amdgcn_mfma_f32_16x16x32_bf16(af.s8, b0, acc0, 0, 0, 0);
        acc1 = __builtin_amdgcn_mfma_f32_16x16x32_bf16(af.s8, b1, acc1, 0, 0, 0);
        accd = __builtin_amdgcn_mfma_f32_16x16x32_bf16(af.s8, ones.s8, accd, 0, 0, 0);
    }

    // C/D layout: col = lane&15 (= r), row = q*4 + reg
#pragma unroll
    for (int reg = 0; reg < 4; ++reg) {
        int nrow = n0 + wid * 16 + q * 4 + reg;
        float inv = 1.0f / accd[reg];
        float* op = out + ((size_t)(b * NN + nrow)) * FF + head * DD;
        op[r]      = acc0[reg] * inv;
        op[16 + r] = acc1[reg] * inv;
    }
}

extern "C" void kernel_launch(void* const* d_in, const int* in_sizes, int n_in,
                              void* d_out, int out_size, void* d_ws, size_t ws_size,
                              hipStream_t stream) {
    const float* x     = (const float*)d_in[0];
    const int*   adj   = (const int*)d_in[1];
    const float* W     = (const float*)d_in[2];
    const float* a_src = (const float*)d_in[3];
    const float* a_dst = (const float*)d_in[4];
    float* out = (float*)d_out;

    float* h    = (float*)d_ws;                          // 1,048,576 f
    float* es_t = h + (size_t)BB * NN * FF;              // 32,768 f
    float* ed_t = es_t + (size_t)BB * HH * NN;           // 32,768 f
    unsigned int* bits = (unsigned int*)(ed_t + (size_t)BB * HH * NN);   // 131,072 u32
    unsigned short* ht = (unsigned short*)(bits + (size_t)NN * (NN / 32)); // 2,097,152 bf16

    hipLaunchKernelGGL(k_pack_adj, dim3(NN * (NN / 32) / 256), dim3(256), 0, stream,
                       adj, bits);
    hipLaunchKernelGGL(k_gemm_h, dim3(BB * NN / 16), dim3(256), 0, stream, x, W, h);
    hipLaunchKernelGGL(k_edges, dim3(BB * NN * HH / 256), dim3(256), 0, stream,
                       h, a_src, a_dst, es_t, ed_t);
    hipLaunchKernelGGL(k_ht, dim3(NN / 128, BB * HH), dim3(256), 0, stream, h, ht);
    hipLaunchKernelGGL(k_attn, dim3(NN / 128, BB * HH), dim3(512), 0, stream,
                       ht, bits, es_t, ed_t, out);
}

// Round 3
// 106.293 us; speedup vs baseline: 1.9191x; 1.0503x over previous
//
#include <hip/hip_runtime.h>
#include <math.h>

#define BB 4
#define NN 2048
#define FF 128
#define HH 4
#define DD 32
#define NEG_SLOPE 0.2f
#define LOG2E 1.4426950408889634f

typedef __attribute__((ext_vector_type(8))) short short8;
typedef __attribute__((ext_vector_type(4))) float floatx4;

__device__ __forceinline__ float exp2_fast(float x) {
#if __has_builtin(__builtin_amdgcn_exp2f)
    return __builtin_amdgcn_exp2f(x);
#else
    return exp2f(x);
#endif
}

__device__ __forceinline__ unsigned short to_bf16(float f) {
    unsigned int ui = __float_as_uint(f);
    ui += 0x7FFFu + ((ui >> 16) & 1u);   // RTNE
    return (unsigned short)(ui >> 16);
}

// ---------------- K1: pack adj rows into bitmask words bits[n][NN/32]
__global__ __launch_bounds__(256) void k_pack_adj(const int* __restrict__ adj,
                                                  unsigned int* __restrict__ bits) {
    int idx = blockIdx.x * 256 + threadIdx.x;   // 0 .. N*64-1
    int n = idx >> 6, w = idx & 63;
    const int4* base = (const int4*)(adj + (size_t)n * NN + w * 32);
    unsigned int word = 0;
#pragma unroll
    for (int q = 0; q < 8; ++q) {
        int4 a = base[q];
        word |= ((unsigned int)(a.x & 1)) << (q * 4 + 0);
        word |= ((unsigned int)(a.y & 1)) << (q * 4 + 1);
        word |= ((unsigned int)(a.z & 1)) << (q * 4 + 2);
        word |= ((unsigned int)(a.w & 1)) << (q * 4 + 3);
    }
    bits[idx] = word;
}

// ---------------- K2: fused  h = x@W^T  ->  {ht (bf16, [bh][d][m]),  es_t/ed_t (prescaled)}
// 16 rows/block, 256 threads, grid 512. fp32 h never hits global memory.
__global__ __launch_bounds__(256) void k_gemm_fused(const float* __restrict__ x,
                                                    const float* __restrict__ W,
                                                    const float* __restrict__ a_src,
                                                    const float* __restrict__ a_dst,
                                                    unsigned short* __restrict__ ht,
                                                    float* __restrict__ es_t,
                                                    float* __restrict__ ed_t) {
    __shared__ float xs[16][FF];
    __shared__ float wt[32][132];            // [i_local][o], pad 4
    __shared__ float as_s[FF], ad_s[FF];
    __shared__ unsigned short tile2[16][136]; // [m_local][col], pad 8
    int t = threadIdx.x;
    long rows0 = (long)blockIdx.x * 16;
    if (t < FF) { as_s[t] = a_src[t]; ad_s[t] = a_dst[t]; }
#pragma unroll
    for (int k = 0; k < 2; ++k) {            // stage x: 512 float4
        int q = t + k * 256;
        int r = q >> 5, c4 = q & 31;
        float4 v = ((const float4*)(x + (rows0 + r) * FF))[c4];
        *(float4*)&xs[r][c4 * 4] = v;
    }
    int og = t & 31, rg = t >> 5;            // cols og*4.., rows rg*2..
    float acc[2][4];
#pragma unroll
    for (int a = 0; a < 2; ++a)
#pragma unroll
        for (int c = 0; c < 4; ++c) acc[a][c] = 0.f;

    int wo = t & 127, wg = t >> 7;
    for (int i0 = 0; i0 < FF; i0 += 32) {
        __syncthreads();
#pragma unroll
        for (int u = 0; u < 4; ++u) {        // stage W[o][i0..+31] transposed
            float4 v = *(const float4*)(W + (long)wo * FF + i0 + wg * 16 + u * 4);
            wt[wg * 16 + u * 4 + 0][wo] = v.x;
            wt[wg * 16 + u * 4 + 1][wo] = v.y;
            wt[wg * 16 + u * 4 + 2][wo] = v.z;
            wt[wg * 16 + u * 4 + 3][wo] = v.w;
        }
        __syncthreads();
#pragma unroll
        for (int i = 0; i < 32; ++i) {
            float4 w4 = *(const float4*)&wt[i][og * 4];
            float x0 = xs[rg * 2 + 0][i0 + i];
            float x1 = xs[rg * 2 + 1][i0 + i];
            acc[0][0] += x0 * w4.x; acc[0][1] += x0 * w4.y;
            acc[0][2] += x0 * w4.z; acc[0][3] += x0 * w4.w;
            acc[1][0] += x1 * w4.x; acc[1][1] += x1 * w4.y;
            acc[1][2] += x1 * w4.z; acc[1][3] += x1 * w4.w;
        }
    }

    // ---- epilogue a: edge scores (fp32, reduced over each head's 8 og-lanes)
    int head = og >> 3;
    int b = (int)(rows0 >> 11);              // block never straddles batches
    int m_block = (int)(rows0 & 2047);
    float es0 = 0.f, ed0 = 0.f, es1 = 0.f, ed1 = 0.f;
#pragma unroll
    for (int c = 0; c < 4; ++c) {
        int col = og * 4 + c;
        es0 += acc[0][c] * as_s[col]; ed0 += acc[0][c] * ad_s[col];
        es1 += acc[1][c] * as_s[col]; ed1 += acc[1][c] * ad_s[col];
    }
#pragma unroll
    for (int k = 1; k < 8; k <<= 1) {        // reduce within 8-lane head group
        es0 += __shfl_xor(es0, k); ed0 += __shfl_xor(ed0, k);
        es1 += __shfl_xor(es1, k); ed1 += __shfl_xor(ed1, k);
    }
    if ((og & 7) == 0) {
        size_t eb = (size_t)(b * HH + head) * NN + m_block + rg * 2;
        es_t[eb]     = es0 * LOG2E; ed_t[eb]     = ed0 * LOG2E;
        es_t[eb + 1] = es1 * LOG2E; ed_t[eb + 1] = ed1 * LOG2E;
    }

    // ---- epilogue b: bf16 transpose -> ht[bh][d][m]
#pragma unroll
    for (int a = 0; a < 2; ++a)
#pragma unroll
        for (int c = 0; c < 4; ++c)
            tile2[rg * 2 + a][og * 4 + c] = to_bf16(acc[a][c]);
    __syncthreads();
    {
        int cg = t >> 1, half = t & 1;       // cg: 0..127 global col, half: m 0..7 / 8..15
        int d = cg & 31, hd = cg >> 5;
        unsigned short tmp[8];
#pragma unroll
        for (int j = 0; j < 8; ++j) tmp[j] = tile2[half * 8 + j][cg];
        unsigned short* op = ht + ((size_t)(b * HH + hd) * DD + d) * NN + m_block + half * 8;
        *(int4*)op = *(const int4*)tmp;
    }
}

// ---------------- K3: fused masked-softmax attention + PV via MFMA
// grid (16 n-blocks, 16 bh), 512 threads (8 waves), 1 block/CU (106KB LDS).
// bits + e_dst + half-of-ht staged in LDS; m-loop has ZERO global loads.
#define HB_HALF 1024
__global__ __launch_bounds__(512) void k_attn(
        const unsigned short* __restrict__ ht,
        const unsigned int* __restrict__ bits,
        const float* __restrict__ es_t,
        const float* __restrict__ ed_t,
        float* __restrict__ out) {
    __shared__ unsigned short hb[DD * HB_HALF];   // 64 KB, XOR-swizzled 16B chunks
    __shared__ float eds[NN];                      // 8 KB
    __shared__ unsigned int bitw[128][68];         // 34 KB (uses [][0..63])
    int t = threadIdx.x;
    int n0 = blockIdx.x * 128;
    int bh = blockIdx.y;
    int b = bh >> 2, head = bh & 3;

    // stage e_dst' (prescaled by log2 e)
    ((float4*)eds)[t] = ((const float4*)(ed_t + (size_t)bh * NN))[t];
    // stage adjacency bit-rows for this block's 128 n
#pragma unroll
    for (int k = 0; k < 4; ++k) {
        int q = t + k * 512;                 // 2048 int4 chunks
        int nl = q >> 4, wq = q & 15;
        int4 v = ((const int4*)(bits + (size_t)(n0 + nl) * 64))[wq];
        *(int4*)&bitw[nl][wq * 4] = v;       // stride 68 ≡ 0 mod 4 -> aligned
    }

    int wid = t >> 6, lane = t & 63;
    int q = lane >> 4, r = lane & 15;
    int qo = q * 8, sw = r & 7;
    int n_l = wid * 16 + r;
    float es = es_t[(size_t)bh * NN + n0 + n_l];
    const unsigned short* htp = ht + (size_t)bh * DD * NN;

    floatx4 acc0 = {0.f, 0.f, 0.f, 0.f};
    floatx4 acc1 = {0.f, 0.f, 0.f, 0.f};
    floatx4 accd = {0.f, 0.f, 0.f, 0.f};
    union { short8 s8; int i[4]; } ones;
    ones.i[0] = 0x3F803F80; ones.i[1] = 0x3F803F80;
    ones.i[2] = 0x3F803F80; ones.i[3] = 0x3F803F80;

    for (int half = 0; half < 2; ++half) {
        __syncthreads();                      // hb reuse guard (and staging visibility)
        // stage half of ht: 4096 int4 chunks, XOR-swizzled by (d&7)
#pragma unroll
        for (int k = 0; k < 8; ++k) {
            int qq = t + k * 512;
            int d = qq >> 7, cm = qq & 127;
            int4 v = *(const int4*)(htp + (size_t)d * NN + half * HB_HALF + cm * 8);
            *(int4*)&hb[d * HB_HALF + ((cm ^ (d & 7)) * 8)] = v;
        }
        __syncthreads();
        const unsigned int* brow = bitw[n_l];
#pragma unroll 2
        for (int m0 = 0; m0 < HB_HALF; m0 += 32) {
            int mg = half * HB_HALF + m0;
            unsigned int word = brow[mg >> 5];
            float4 e0 = *(const float4*)&eds[mg + qo];
            float4 e1 = *(const float4*)&eds[mg + qo + 4];
            float w[8];
#pragma unroll
            for (int j = 0; j < 8; ++j) {
                float ev = j < 4 ? (&e0.x)[j] : (&e1.x)[j - 4];
                float s = es + ev;
                float l = fmaxf(s, NEG_SLOPE * s);
                float v = exp2_fast(l);
                w[j] = (word & (1u << (qo + j))) ? v : 0.f;
            }
            union { short8 s8; int i[4]; } af;
#pragma unroll
            for (int p = 0; p < 4; ++p)
                af.i[p] = __builtin_amdgcn_perm(__float_as_uint(w[2 * p + 1]),
                                                __float_as_uint(w[2 * p]),
                                                0x07060302u);
            int cs = ((m0 + qo) >> 3) ^ sw;   // swizzled chunk index
            short8 b0 = *(const short8*)&hb[r * HB_HALF + cs * 8];
            short8 b1 = *(const short8*)&hb[(16 + r) * HB_HALF + cs * 8];
            acc0 = __builtin_amdgcn_mfma_f32_16x16x32_bf16(af.s8, b0, acc0, 0, 0, 0);
            acc1 = __builtin_amdgcn_mfma_f32_16x16x32_bf16(af.s8, b1, acc1, 0, 0, 0);
            accd = __builtin_amdgcn_mfma_f32_16x16x32_bf16(af.s8, ones.s8, accd, 0, 0, 0);
        }
    }

    // C/D layout: col = lane&15 (= r), row = q*4 + reg
#pragma unroll
    for (int reg = 0; reg < 4; ++reg) {
        int nrow = n0 + wid * 16 + q * 4 + reg;
        float inv = 1.0f / accd[reg];
        float* op = out + ((size_t)(b * NN + nrow)) * FF + head * DD;
        op[r]      = acc0[reg] * inv;
        op[16 + r] = acc1[reg] * inv;
    }
}

extern "C" void kernel_launch(void* const* d_in, const int* in_sizes, int n_in,
                              void* d_out, int out_size, void* d_ws, size_t ws_size,
                              hipStream_t stream) {
    const float* x     = (const float*)d_in[0];
    const int*   adj   = (const int*)d_in[1];
    const float* W     = (const float*)d_in[2];
    const float* a_src = (const float*)d_in[3];
    const float* a_dst = (const float*)d_in[4];
    float* out = (float*)d_out;

    float* es_t = (float*)d_ws;                                // 32,768 f
    float* ed_t = es_t + (size_t)BB * HH * NN;                 // 32,768 f
    unsigned int* bits = (unsigned int*)(ed_t + (size_t)BB * HH * NN);     // 131,072 u32
    unsigned short* ht = (unsigned short*)(bits + (size_t)NN * (NN / 32)); // 2,097,152 bf16

    hipLaunchKernelGGL(k_pack_adj, dim3(NN * (NN / 32) / 256), dim3(256), 0, stream,
                       adj, bits);
    hipLaunchKernelGGL(k_gemm_fused, dim3(BB * NN / 16), dim3(256), 0, stream,
                       x, W, a_src, a_dst, ht, es_t, ed_t);
    hipLaunchKernelGGL(k_attn, dim3(NN / 128, BB * HH), dim3(512), 0, stream,
                       ht, bits, es_t, ed_t, out);
}

// Round 4
// 104.620 us; speedup vs baseline: 1.9498x; 1.0160x over previous
//
#include <hip/hip_runtime.h>
#include <math.h>

#define BB 4
#define NN 2048
#define FF 128
#define HH 4
#define DD 32
#define NEG_SLOPE 0.2f
#define LOG2E 1.4426950408889634f

typedef __attribute__((ext_vector_type(8))) short short8;
typedef __attribute__((ext_vector_type(4))) float floatx4;

__device__ __forceinline__ float exp2_fast(float x) {
#if __has_builtin(__builtin_amdgcn_exp2f)
    return __builtin_amdgcn_exp2f(x);
#else
    return exp2f(x);
#endif
}

__device__ __forceinline__ unsigned short to_bf16(float f) {
    unsigned int ui = __float_as_uint(f);
    ui += 0x7FFFu + ((ui >> 16) & 1u);   // RTNE
    return (unsigned short)(ui >> 16);
}

// ---------------- K1: prep = {gemm_fused (blocks 0..511), pack_adj (512..1023)}
// gemm: h = x@W^T -> ht (bf16 [bh][d][m]) + es_t/ed_t (prescaled by log2 e).
// pack: adj rows -> bitmask words bits[n][64].
__global__ __launch_bounds__(256) void k_prep(const float* __restrict__ x,
                                              const float* __restrict__ W,
                                              const float* __restrict__ a_src,
                                              const float* __restrict__ a_dst,
                                              const int* __restrict__ adj,
                                              unsigned short* __restrict__ ht,
                                              float* __restrict__ es_t,
                                              float* __restrict__ ed_t,
                                              unsigned int* __restrict__ bits) {
    __shared__ float xs[16][FF];
    __shared__ float wt[32][132];             // [i_local][o], pad 4
    __shared__ float as_s[FF], ad_s[FF];
    __shared__ unsigned short tile2[16][136]; // [m_local][col], pad 8
    int t = threadIdx.x;

    if (blockIdx.x >= 512) {
        // ---- pack_adj ----
        int idx = (blockIdx.x - 512) * 256 + t;     // 0 .. N*64-1
        int n = idx >> 6, w = idx & 63;
        const int4* base = (const int4*)(adj + (size_t)n * NN + w * 32);
        unsigned int word = 0;
#pragma unroll
        for (int q = 0; q < 8; ++q) {
            int4 a = base[q];
            word |= ((unsigned int)(a.x & 1)) << (q * 4 + 0);
            word |= ((unsigned int)(a.y & 1)) << (q * 4 + 1);
            word |= ((unsigned int)(a.z & 1)) << (q * 4 + 2);
            word |= ((unsigned int)(a.w & 1)) << (q * 4 + 3);
        }
        bits[idx] = word;
        return;
    }

    // ---- gemm_fused ----
    long rows0 = (long)blockIdx.x * 16;
    if (t < FF) { as_s[t] = a_src[t]; ad_s[t] = a_dst[t]; }
#pragma unroll
    for (int k = 0; k < 2; ++k) {             // stage x: 512 float4
        int q = t + k * 256;
        int r = q >> 5, c4 = q & 31;
        float4 v = ((const float4*)(x + (rows0 + r) * FF))[c4];
        *(float4*)&xs[r][c4 * 4] = v;
    }
    int og = t & 31, rg = t >> 5;             // cols og*4.., rows rg*2..
    float acc[2][4];
#pragma unroll
    for (int a = 0; a < 2; ++a)
#pragma unroll
        for (int c = 0; c < 4; ++c) acc[a][c] = 0.f;

    int wo = t & 127, wg = t >> 7;
    for (int i0 = 0; i0 < FF; i0 += 32) {
        __syncthreads();
#pragma unroll
        for (int u = 0; u < 4; ++u) {         // stage W[o][i0..+31] transposed
            float4 v = *(const float4*)(W + (long)wo * FF + i0 + wg * 16 + u * 4);
            wt[wg * 16 + u * 4 + 0][wo] = v.x;
            wt[wg * 16 + u * 4 + 1][wo] = v.y;
            wt[wg * 16 + u * 4 + 2][wo] = v.z;
            wt[wg * 16 + u * 4 + 3][wo] = v.w;
        }
        __syncthreads();
#pragma unroll
        for (int i = 0; i < 32; ++i) {
            float4 w4 = *(const float4*)&wt[i][og * 4];
            float x0 = xs[rg * 2 + 0][i0 + i];
            float x1 = xs[rg * 2 + 1][i0 + i];
            acc[0][0] += x0 * w4.x; acc[0][1] += x0 * w4.y;
            acc[0][2] += x0 * w4.z; acc[0][3] += x0 * w4.w;
            acc[1][0] += x1 * w4.x; acc[1][1] += x1 * w4.y;
            acc[1][2] += x1 * w4.z; acc[1][3] += x1 * w4.w;
        }
    }

    // epilogue a: edge scores (fp32, reduced over each head's 8 og-lanes)
    int head = og >> 3;
    int b = (int)(rows0 >> 11);
    int m_block = (int)(rows0 & 2047);
    float es0 = 0.f, ed0 = 0.f, es1 = 0.f, ed1 = 0.f;
#pragma unroll
    for (int c = 0; c < 4; ++c) {
        int col = og * 4 + c;
        es0 += acc[0][c] * as_s[col]; ed0 += acc[0][c] * ad_s[col];
        es1 += acc[1][c] * as_s[col]; ed1 += acc[1][c] * ad_s[col];
    }
#pragma unroll
    for (int k = 1; k < 8; k <<= 1) {
        es0 += __shfl_xor(es0, k); ed0 += __shfl_xor(ed0, k);
        es1 += __shfl_xor(es1, k); ed1 += __shfl_xor(ed1, k);
    }
    if ((og & 7) == 0) {
        size_t eb = (size_t)(b * HH + head) * NN + m_block + rg * 2;
        es_t[eb]     = es0 * LOG2E; ed_t[eb]     = ed0 * LOG2E;
        es_t[eb + 1] = es1 * LOG2E; ed_t[eb + 1] = ed1 * LOG2E;
    }

    // epilogue b: bf16 transpose -> ht[bh][d][m]
#pragma unroll
    for (int a = 0; a < 2; ++a)
#pragma unroll
        for (int c = 0; c < 4; ++c)
            tile2[rg * 2 + a][og * 4 + c] = to_bf16(acc[a][c]);
    __syncthreads();
    {
        int cg = t >> 1, half = t & 1;
        int d = cg & 31, hd = cg >> 5;
        unsigned short tmp[8];
#pragma unroll
        for (int j = 0; j < 8; ++j) tmp[j] = tile2[half * 8 + j][cg];
        unsigned short* op = ht + ((size_t)(b * HH + hd) * DD + d) * NN + m_block + half * 8;
        *(int4*)op = *(const int4*)tmp;
    }
}

// ---------------- K2: fused masked-softmax attention + PV via MFMA
// grid (16, 16), 1024 threads (16 waves, 4/SIMD), 1 block/CU, 140KB LDS.
// K-split: waves 0-7 handle m in [0,1024), waves 8-15 m in [1024,2048) over
// the same 128 n-rows; pair-reduced via LDS at the end. Adjacency bits live
// in 8 int4 REGISTERS per lane (m-loop fully unrolled -> static indexing).
// m-loop: zero global loads, zero barriers.
#define HTS 2056
__global__ __launch_bounds__(1024, 4) void k_attn(
        const unsigned short* __restrict__ ht,
        const unsigned int* __restrict__ bits,
        const float* __restrict__ es_t,
        const float* __restrict__ ed_t,
        float* __restrict__ out) {
    __shared__ unsigned short hb[DD * HTS];   // 128.5 KB (row pad 8 -> bank offset 4/row)
    __shared__ float eds[NN];                  // 8 KB
    int t = threadIdx.x;
    int n0 = blockIdx.x * 128;
    int bh = blockIdx.y;
    int b = bh >> 2, head = bh & 3;

    int wid = t >> 6, lane = t & 63;
    int q = lane >> 4, r = lane & 15;
    int qo = q * 8;
    int half = wid >> 3, wsub = wid & 7;
    int n_l = wsub * 16 + r;

    // stage e_dst' (512 float4)
    if (t < 512)
        ((float4*)eds)[t] = ((const float4*)(ed_t + (size_t)bh * NN))[t];
    // stage full ht slice: 8192 int4 chunks
    {
        const unsigned short* htp = ht + (size_t)bh * DD * NN;
#pragma unroll
        for (int k = 0; k < 8; ++k) {
            int qq = t + k * 1024;
            int d = qq >> 8, cm = qq & 255;
            int4 v = *(const int4*)(htp + (size_t)d * NN + cm * 8);
            *(int4*)&hb[d * HTS + cm * 8] = v;
        }
    }
    // adjacency bits for this lane's row + K-half: 32 words in registers
    int4 bw[8];
    {
        const int4* bp = (const int4*)(bits + (size_t)(n0 + n_l) * 64 + half * 32);
#pragma unroll
        for (int g = 0; g < 8; ++g) bw[g] = bp[g];
    }
    float es = es_t[(size_t)bh * NN + n0 + n_l];
    __syncthreads();

    floatx4 acc0 = {0.f, 0.f, 0.f, 0.f};
    floatx4 acc1 = {0.f, 0.f, 0.f, 0.f};
    floatx4 accd = {0.f, 0.f, 0.f, 0.f};
    union { short8 s8; int i[4]; } ones;
    ones.i[0] = 0x3F803F80; ones.i[1] = 0x3F803F80;
    ones.i[2] = 0x3F803F80; ones.i[3] = 0x3F803F80;

    const float* edh = eds + half * 1024;
    const unsigned short* hrow0 = &hb[r * HTS + half * 1024 + qo];
    const unsigned short* hrow1 = hrow0 + 16 * HTS;

#pragma unroll
    for (int g = 0; g < 8; ++g) {
#pragma unroll
        for (int c = 0; c < 4; ++c) {
            unsigned int word = (unsigned int)((&bw[g].x)[c]);
            int mb = (g * 4 + c) * 32;
            unsigned int wq = word >> qo;
            float4 e0 = *(const float4*)&edh[mb + qo];
            float4 e1 = *(const float4*)&edh[mb + qo + 4];
            float w[8];
#pragma unroll
            for (int j = 0; j < 8; ++j) {
                float ev = j < 4 ? (&e0.x)[j] : (&e1.x)[j - 4];
                float s = es + ev;
                float l = fmaxf(s, NEG_SLOPE * s);
                float v = exp2_fast(l);
                w[j] = (wq & (1u << j)) ? v : 0.f;
            }
            union { short8 s8; int i[4]; } af;
#pragma unroll
            for (int p = 0; p < 4; ++p)
                af.i[p] = __builtin_amdgcn_perm(__float_as_uint(w[2 * p + 1]),
                                                __float_as_uint(w[2 * p]),
                                                0x07060302u);
            short8 b0 = *(const short8*)(hrow0 + mb);
            short8 b1 = *(const short8*)(hrow1 + mb);
            acc0 = __builtin_amdgcn_mfma_f32_16x16x32_bf16(af.s8, b0, acc0, 0, 0, 0);
            acc1 = __builtin_amdgcn_mfma_f32_16x16x32_bf16(af.s8, b1, acc1, 0, 0, 0);
            accd = __builtin_amdgcn_mfma_f32_16x16x32_bf16(af.s8, ones.s8, accd, 0, 0, 0);
        }
    }

    // K-half pair reduction through LDS (reuse hb as fp32 scratch, 24KB)
    __syncthreads();
    float* scr = (float*)hb;
    if (wid >= 8) {
        int base = ((wid - 8) * 64 + lane) * 12;
        *(floatx4*)&scr[base + 0] = acc0;
        *(floatx4*)&scr[base + 4] = acc1;
        *(floatx4*)&scr[base + 8] = accd;
    }
    __syncthreads();
    if (wid < 8) {
        int base = (wid * 64 + lane) * 12;
        floatx4 p0 = *(const floatx4*)&scr[base + 0];
        floatx4 p1 = *(const floatx4*)&scr[base + 4];
        floatx4 pd = *(const floatx4*)&scr[base + 8];
#pragma unroll
        for (int k = 0; k < 4; ++k) {
            acc0[k] += p0[k]; acc1[k] += p1[k]; accd[k] += pd[k];
        }
        // C/D layout: col = lane&15 (= r), row = q*4 + reg
#pragma unroll
        for (int reg = 0; reg < 4; ++reg) {
            int nrow = n0 + wsub * 16 + q * 4 + reg;
            float inv = 1.0f / accd[reg];
            float* op = out + ((size_t)(b * NN + nrow)) * FF + head * DD;
            op[r]      = acc0[reg] * inv;
            op[16 + r] = acc1[reg] * inv;
        }
    }
}

extern "C" void kernel_launch(void* const* d_in, const int* in_sizes, int n_in,
                              void* d_out, int out_size, void* d_ws, size_t ws_size,
                              hipStream_t stream) {
    const float* x     = (const float*)d_in[0];
    const int*   adj   = (const int*)d_in[1];
    const float* W     = (const float*)d_in[2];
    const float* a_src = (const float*)d_in[3];
    const float* a_dst = (const float*)d_in[4];
    float* out = (float*)d_out;

    float* es_t = (float*)d_ws;                                // 32,768 f
    float* ed_t = es_t + (size_t)BB * HH * NN;                 // 32,768 f
    unsigned int* bits = (unsigned int*)(ed_t + (size_t)BB * HH * NN);     // 131,072 u32
    unsigned short* ht = (unsigned short*)(bits + (size_t)NN * (NN / 32)); // 2,097,152 bf16

    hipLaunchKernelGGL(k_prep, dim3(1024), dim3(256), 0, stream,
                       x, W, a_src, a_dst, adj, ht, es_t, ed_t, bits);
    hipLaunchKernelGGL(k_attn, dim3(NN / 128, BB * HH), dim3(1024), 0, stream,
                       ht, bits, es_t, ed_t, out);
}

// Round 5
// 102.519 us; speedup vs baseline: 1.9897x; 1.0205x over previous
//
#include <hip/hip_runtime.h>
#include <math.h>

#define BB 4
#define NN 2048
#define FF 128
#define HH 4
#define DD 32
#define NEG_SLOPE 0.2f
#define LOG2E 1.4426950408889634f

typedef __attribute__((ext_vector_type(8))) short short8;
typedef __attribute__((ext_vector_type(4))) float floatx4;
typedef __attribute__((ext_vector_type(2))) float floatx2;

__device__ __forceinline__ float exp2_fast(float x) {
#if __has_builtin(__builtin_amdgcn_exp2f)
    return __builtin_amdgcn_exp2f(x);
#else
    return exp2f(x);
#endif
}

__device__ __forceinline__ int bit_mask(unsigned int w, int bit) {
#if __has_builtin(__builtin_amdgcn_sbfe)
    return __builtin_amdgcn_sbfe((int)w, bit, 1);    // v_bfe_i32: 0 or -1
#else
    return ((int)(w << (31 - bit))) >> 31;
#endif
}

__device__ __forceinline__ unsigned short to_bf16(float f) {
    unsigned int ui = __float_as_uint(f);
    ui += 0x7FFFu + ((ui >> 16) & 1u);   // RTNE
    return (unsigned short)(ui >> 16);
}

// ---------------- K1: prep = {gemm_fused (blocks 0..511), pack_adj (512..1023)}
__global__ __launch_bounds__(256) void k_prep(const float* __restrict__ x,
                                              const float* __restrict__ W,
                                              const float* __restrict__ a_src,
                                              const float* __restrict__ a_dst,
                                              const int* __restrict__ adj,
                                              unsigned short* __restrict__ ht,
                                              float* __restrict__ es_t,
                                              float* __restrict__ ed_t,
                                              unsigned int* __restrict__ bits) {
    __shared__ float xs[16][FF];
    __shared__ float wt[32][132];
    __shared__ float as_s[FF], ad_s[FF];
    __shared__ unsigned short tile2[16][136];
    int t = threadIdx.x;

    if (blockIdx.x >= 512) {
        int idx = (blockIdx.x - 512) * 256 + t;
        int n = idx >> 6, w = idx & 63;
        const int4* base = (const int4*)(adj + (size_t)n * NN + w * 32);
        unsigned int word = 0;
#pragma unroll
        for (int q = 0; q < 8; ++q) {
            int4 a = base[q];
            word |= ((unsigned int)(a.x & 1)) << (q * 4 + 0);
            word |= ((unsigned int)(a.y & 1)) << (q * 4 + 1);
            word |= ((unsigned int)(a.z & 1)) << (q * 4 + 2);
            word |= ((unsigned int)(a.w & 1)) << (q * 4 + 3);
        }
        bits[idx] = word;
        return;
    }

    long rows0 = (long)blockIdx.x * 16;
    if (t < FF) { as_s[t] = a_src[t]; ad_s[t] = a_dst[t]; }
#pragma unroll
    for (int k = 0; k < 2; ++k) {
        int q = t + k * 256;
        int r = q >> 5, c4 = q & 31;
        float4 v = ((const float4*)(x + (rows0 + r) * FF))[c4];
        *(float4*)&xs[r][c4 * 4] = v;
    }
    int og = t & 31, rg = t >> 5;
    float acc[2][4];
#pragma unroll
    for (int a = 0; a < 2; ++a)
#pragma unroll
        for (int c = 0; c < 4; ++c) acc[a][c] = 0.f;

    int wo = t & 127, wg = t >> 7;
    for (int i0 = 0; i0 < FF; i0 += 32) {
        __syncthreads();
#pragma unroll
        for (int u = 0; u < 4; ++u) {
            float4 v = *(const float4*)(W + (long)wo * FF + i0 + wg * 16 + u * 4);
            wt[wg * 16 + u * 4 + 0][wo] = v.x;
            wt[wg * 16 + u * 4 + 1][wo] = v.y;
            wt[wg * 16 + u * 4 + 2][wo] = v.z;
            wt[wg * 16 + u * 4 + 3][wo] = v.w;
        }
        __syncthreads();
#pragma unroll
        for (int i = 0; i < 32; ++i) {
            float4 w4 = *(const float4*)&wt[i][og * 4];
            float x0 = xs[rg * 2 + 0][i0 + i];
            float x1 = xs[rg * 2 + 1][i0 + i];
            acc[0][0] += x0 * w4.x; acc[0][1] += x0 * w4.y;
            acc[0][2] += x0 * w4.z; acc[0][3] += x0 * w4.w;
            acc[1][0] += x1 * w4.x; acc[1][1] += x1 * w4.y;
            acc[1][2] += x1 * w4.z; acc[1][3] += x1 * w4.w;
        }
    }

    int head = og >> 3;
    int b = (int)(rows0 >> 11);
    int m_block = (int)(rows0 & 2047);
    float es0 = 0.f, ed0 = 0.f, es1 = 0.f, ed1 = 0.f;
#pragma unroll
    for (int c = 0; c < 4; ++c) {
        int col = og * 4 + c;
        es0 += acc[0][c] * as_s[col]; ed0 += acc[0][c] * ad_s[col];
        es1 += acc[1][c] * as_s[col]; ed1 += acc[1][c] * ad_s[col];
    }
#pragma unroll
    for (int k = 1; k < 8; k <<= 1) {
        es0 += __shfl_xor(es0, k); ed0 += __shfl_xor(ed0, k);
        es1 += __shfl_xor(es1, k); ed1 += __shfl_xor(ed1, k);
    }
    if ((og & 7) == 0) {
        size_t eb = (size_t)(b * HH + head) * NN + m_block + rg * 2;
        es_t[eb]     = es0 * LOG2E; ed_t[eb]     = ed0 * LOG2E;
        es_t[eb + 1] = es1 * LOG2E; ed_t[eb + 1] = ed1 * LOG2E;
    }

#pragma unroll
    for (int a = 0; a < 2; ++a)
#pragma unroll
        for (int c = 0; c < 4; ++c)
            tile2[rg * 2 + a][og * 4 + c] = to_bf16(acc[a][c]);
    __syncthreads();
    {
        int cg = t >> 1, half = t & 1;
        int d = cg & 31, hd = cg >> 5;
        unsigned short tmp[8];
#pragma unroll
        for (int j = 0; j < 8; ++j) tmp[j] = tile2[half * 8 + j][cg];
        unsigned short* op = ht + ((size_t)(b * HH + hd) * DD + d) * NN + m_block + half * 8;
        *(int4*)op = *(const int4*)tmp;
    }
}

// ---------------- K2: fused masked-softmax attention + PV via MFMA
// Inner loop is transcendental-free:
//   exp2(leaky(es+ed)) = max(exp2(es)*exp2(ed), exp2(.2es)*exp2(.2ed))
// Per-m pairs (Ed_p,Ed_n) precomputed in LDS; per-lane (Es_p,Es_n) hoisted.
// Per element: v_pk_mul_f32 + v_max + v_bfe_i32 + v_and (~7 cyc vs ~18).
// grid (16,16), 1024 thr (16 waves, K-split halves), 1 block/CU, 144.5KB LDS.
#define HTS 2056
__global__ __launch_bounds__(1024) void k_attn(
        const unsigned short* __restrict__ ht,
        const unsigned int* __restrict__ bits,
        const float* __restrict__ es_t,
        const float* __restrict__ ed_t,
        float* __restrict__ out) {
    __shared__ unsigned short hb[DD * HTS];   // 128.5 KB
    __shared__ float ep[NN * 2];               // 16 KB: (Ed_p, Ed_n) per m
    int t = threadIdx.x;
    int n0 = blockIdx.x * 128;
    int bh = blockIdx.y;
    int b = bh >> 2, head = bh & 3;

    int wid = t >> 6, lane = t & 63;
    int q = lane >> 4, r = lane & 15;
    int qo = q * 8;
    int half = wid >> 3, wsub = wid & 7;
    int n_l = wsub * 16 + r;

    // stage (Ed_p, Ed_n) pairs: 2 m per thread
    {
        float2 v = ((const float2*)(ed_t + (size_t)bh * NN))[t];
        float4 o;
        o.x = exp2_fast(v.x); o.y = exp2_fast(NEG_SLOPE * v.x);
        o.z = exp2_fast(v.y); o.w = exp2_fast(NEG_SLOPE * v.y);
        ((float4*)ep)[t] = o;
    }
    // stage full ht slice: 8192 int4 chunks
    {
        const unsigned short* htp = ht + (size_t)bh * DD * NN;
#pragma unroll
        for (int k = 0; k < 8; ++k) {
            int qq = t + k * 1024;
            int d = qq >> 8, cm = qq & 255;
            int4 v = *(const int4*)(htp + (size_t)d * NN + cm * 8);
            *(int4*)&hb[d * HTS + cm * 8] = v;
        }
    }
    // adjacency bits for this lane's row + K-half: 32 words in registers
    int4 bw[8];
    {
        const int4* bp = (const int4*)(bits + (size_t)(n0 + n_l) * 64 + half * 32);
#pragma unroll
        for (int g = 0; g < 8; ++g) bw[g] = bp[g];
    }
    float esv = es_t[(size_t)bh * NN + n0 + n_l];
    floatx2 es2 = {exp2_fast(esv), exp2_fast(NEG_SLOPE * esv)};
    __syncthreads();

    floatx4 acc0 = {0.f, 0.f, 0.f, 0.f};
    floatx4 acc1 = {0.f, 0.f, 0.f, 0.f};
    floatx4 accd = {0.f, 0.f, 0.f, 0.f};
    union { short8 s8; int i[4]; } ones;
    ones.i[0] = 0x3F803F80; ones.i[1] = 0x3F803F80;
    ones.i[2] = 0x3F803F80; ones.i[3] = 0x3F803F80;

    const float* eph = ep + half * 2048;                       // pairs, this half
    const unsigned short* hrow0 = &hb[r * HTS + half * 1024 + qo];
    const unsigned short* hrow1 = hrow0 + 16 * HTS;

#pragma unroll
    for (int g = 0; g < 8; ++g) {
#pragma unroll
        for (int c = 0; c < 4; ++c) {
            unsigned int word = (unsigned int)((&bw[g].x)[c]);
            int mb = (g * 4 + c) * 32;
            unsigned int wq = word >> qo;
            const float* pbase = eph + (mb + qo) * 2;
            union { short8 s8; int i[4]; } af;
#pragma unroll
            for (int jp = 0; jp < 4; ++jp) {
                float4 d2 = *(const float4*)(pbase + jp * 4);  // Edp0,Edn0,Edp1,Edn1
                floatx2 p0 = es2 * (floatx2){d2.x, d2.y};      // v_pk_mul_f32
                floatx2 p1 = es2 * (floatx2){d2.z, d2.w};
                float w0 = fmaxf(p0.x, p0.y);
                float w1 = fmaxf(p1.x, p1.y);
                int m0 = bit_mask(wq, 2 * jp);
                int m1 = bit_mask(wq, 2 * jp + 1);
                w0 = __uint_as_float(__float_as_uint(w0) & (unsigned int)m0);
                w1 = __uint_as_float(__float_as_uint(w1) & (unsigned int)m1);
                af.i[jp] = __builtin_amdgcn_perm(__float_as_uint(w1),
                                                 __float_as_uint(w0),
                                                 0x07060302u);
            }
            short8 b0 = *(const short8*)(hrow0 + mb);
            short8 b1 = *(const short8*)(hrow1 + mb);
            acc0 = __builtin_amdgcn_mfma_f32_16x16x32_bf16(af.s8, b0, acc0, 0, 0, 0);
            acc1 = __builtin_amdgcn_mfma_f32_16x16x32_bf16(af.s8, b1, acc1, 0, 0, 0);
            accd = __builtin_amdgcn_mfma_f32_16x16x32_bf16(af.s8, ones.s8, accd, 0, 0, 0);
        }
    }

    // K-half pair reduction through LDS (reuse hb as fp32 scratch, 24KB)
    __syncthreads();
    float* scr = (float*)hb;
    if (wid >= 8) {
        int base = ((wid - 8) * 64 + lane) * 12;
        *(floatx4*)&scr[base + 0] = acc0;
        *(floatx4*)&scr[base + 4] = acc1;
        *(floatx4*)&scr[base + 8] = accd;
    }
    __syncthreads();
    if (wid < 8) {
        int base = (wid * 64 + lane) * 12;
        floatx4 p0 = *(const floatx4*)&scr[base + 0];
        floatx4 p1 = *(const floatx4*)&scr[base + 4];
        floatx4 pd = *(const floatx4*)&scr[base + 8];
#pragma unroll
        for (int k = 0; k < 4; ++k) {
            acc0[k] += p0[k]; acc1[k] += p1[k]; accd[k] += pd[k];
        }
        // C/D layout: col = lane&15 (= r), row = q*4 + reg
#pragma unroll
        for (int reg = 0; reg < 4; ++reg) {
            int nrow = n0 + wsub * 16 + q * 4 + reg;
            float inv = 1.0f / accd[reg];
            float* op = out + ((size_t)(b * NN + nrow)) * FF + head * DD;
            op[r]      = acc0[reg] * inv;
            op[16 + r] = acc1[reg] * inv;
        }
    }
}

extern "C" void kernel_launch(void* const* d_in, const int* in_sizes, int n_in,
                              void* d_out, int out_size, void* d_ws, size_t ws_size,
                              hipStream_t stream) {
    const float* x     = (const float*)d_in[0];
    const int*   adj   = (const int*)d_in[1];
    const float* W     = (const float*)d_in[2];
    const float* a_src = (const float*)d_in[3];
    const float* a_dst = (const float*)d_in[4];
    float* out = (float*)d_out;

    float* es_t = (float*)d_ws;                                // 32,768 f
    float* ed_t = es_t + (size_t)BB * HH * NN;                 // 32,768 f
    unsigned int* bits = (unsigned int*)(ed_t + (size_t)BB * HH * NN);     // 131,072 u32
    unsigned short* ht = (unsigned short*)(bits + (size_t)NN * (NN / 32)); // 2,097,152 bf16

    hipLaunchKernelGGL(k_prep, dim3(1024), dim3(256), 0, stream,
                       x, W, a_src, a_dst, adj, ht, es_t, ed_t, bits);
    hipLaunchKernelGGL(k_attn, dim3(NN / 128, BB * HH), dim3(1024), 0, stream,
                       ht, bits, es_t, ed_t, out);
}